// Round 8
// baseline (8659.608 us; speedup 1.0000x reference)
//
#include <hip/hip_runtime.h>
#include <hip/hip_bf16.h>

#define NEGF (-1000000000.0f)

namespace {

constexpr int B  = 64;
constexpr int N  = 50;
constexpr int NT = 30;
constexpr int T  = 60;
constexpr int S  = 90;          // NT + T
constexpr int NP1 = N + 1;      // 51
constexpr int NSMAX = N - 1;    // 49
constexpr int SS = S * S;       // 8100
constexpr int CELLS = NT * NSMAX; // 1470

// ---- padded K layout ----
constexpr int KP  = 96;          // padded r-dim per l (zero pads at r>=90)
constexpr int KK  = S * KP;      // 8640
constexpr int KSPL = 9;          // split-K chunks
constexpr int KT2 = 64;          // K-tile per LDS staging step
constexpr int NKT = KK / KT2;    // 135
constexpr int TPC = NKT / KSPL;  // 15 tiles per chunk
constexpr int MLSTR = 72;        // LDS row stride (shorts); 144B: b128-aligned, 2-way banks
constexpr int MAROWS = 32;
constexpr int MBROWS = 64;
constexpr int AOFFE = MAROWS * MLSTR;
constexpr int MTOT  = (MAROWS + MBROWS) * MLSTR;   // 6912 shorts = 13.8 KB

// ---- stage1 MFMA layout ----
constexpr int S1R = 96;          // padded state rows (l or r): 6 tiles of 16
constexpr int S1STR = 72;        // row stride in shorts (144B, b128-aligned)

using bf16x8 = __attribute__((ext_vector_type(8))) short;
using f32x4  = __attribute__((ext_vector_type(4))) float;

__global__ void fill_neg(float* __restrict__ p, int count){
  int i = blockIdx.x * blockDim.x + threadIdx.x;
  if (i < count) p[i] = NEGF;
}

__global__ void zero_counters(int* __restrict__ c){
  if (threadIdx.x < B) c[threadIdx.x] = 0;
}

// width-1 spans: terminal states get unary scores; also per-span state-max mb.
__global__ void unary_init(const float* __restrict__ unary, float* __restrict__ beta,
                           float* __restrict__ mb){
  int k = blockIdx.x, b = blockIdx.y, j = threadIdx.x;
  float v = NEGF;
  if (j < T){
    v = unary[(b*N + k)*T + j];
    beta[((b*NP1 + k)*NP1 + (k+1))*S + NT + j] = v;
  }
  #pragma unroll
  for (int off = 32; off > 0; off >>= 1) v = fmaxf(v, __shfl_down(v, off));
  if (j == 0) mb[(b*NP1 + k)*NP1 + (k+1)] = v;
}

// Single-pass (LDS-cached) rule prep: m_rule and erule (bf16, zero pads r>=90).
__global__ __launch_bounds__(256) void rule_prep(const float* __restrict__ rule,
                                                 float* __restrict__ m_rule,
                                                 __hip_bfloat16* __restrict__ erule){
  int p = blockIdx.x, b = blockIdx.y, tid = threadIdx.x;
  int base = (b*NT + p) * SS;
  size_t obase = ((size_t)(b*NT + p)) * KK;
  __shared__ float srule[SS];   // 32.4 KB
  float lm = NEGF;
  for (int i = tid; i < SS; i += 256){
    float v = rule[base + i];
    srule[i] = v;
    lm = fmaxf(lm, v);
  }
  #pragma unroll
  for (int off = 32; off > 0; off >>= 1) lm = fmaxf(lm, __shfl_xor(lm, off));
  __shared__ float wmax[4];
  __shared__ float sm;
  if ((tid & 63) == 0) wmax[tid >> 6] = lm;
  __syncthreads();
  if (tid == 0){
    float m = fmaxf(fmaxf(wmax[0], wmax[1]), fmaxf(wmax[2], wmax[3]));
    m_rule[b*NT + p] = m;
    sm = m;
  }
  __syncthreads();
  float m = sm;
  for (int i = tid; i < KK; i += 256){
    int l = i / KP, rr = i - l * KP;
    float v = (rr < S) ? __expf(srule[l*S + rr] - m) : 0.f;
    erule[obase + i] = __float2bfloat16(v);
  }
}

// Per span (b,s) of width w: O[l,r] = sum_k el[k,l]*er[k,r] via MFMA.
// el/er staged transposed+bf16 in LDS ([96 states][Kpad<=64]); fragment/C-D
// maps are the ones HW-verified by the R6 synth probe.
__global__ __launch_bounds__(256) void stage1(int w, const float* __restrict__ beta,
                                              const float* __restrict__ mb,
                                              float* __restrict__ Mbuf,
                                              __hip_bfloat16* __restrict__ Og){
  int s = blockIdx.x, b = blockIdx.y, e = s + w, tid = threadIdx.x;
  int K = w - 1;
  int Kpad = (K + 31) & ~31;          // 32 or 64
  __shared__ float smr[NSMAX];
  __shared__ float stmp[NSMAX];
  __shared__ float sM;
  __shared__ __align__(16) short elT[S1R * S1STR];  // 13.8 KB
  __shared__ __align__(16) short erT[S1R * S1STR];  // 13.8 KB

  if (tid < K){
    int u = s + tid + 1;
    float ml = mb[(b*NP1 + s)*NP1 + u];
    float mr = mb[(b*NP1 + u)*NP1 + e];
    smr[tid] = mr;
    stmp[tid] = ml + mr;
  }
  __syncthreads();
  if (tid == 0){
    float M = NEGF;
    for (int k = 0; k < K; ++k) M = fmaxf(M, stmp[k]);
    sM = M;
    Mbuf[b*NSMAX + s] = M;
  }
  __syncthreads();
  float M = sM;

  // stage el/er (bf16, transposed); zero where k>=K or i>=90
  int items = S1R * Kpad;
  for (int idx = tid; idx < items; idx += 256){
    int k = idx / S1R, i = idx - k * S1R;   // i fastest -> coalesced beta reads
    short ve = 0, vr = 0;
    if (i < S && k < K){
      int u = s + k + 1;
      float mr = smr[k];
      float lv = beta[((b*NP1 + s)*NP1 + u)*S + i];
      float rv = beta[((b*NP1 + u)*NP1 + e)*S + i];
      __hip_bfloat16 he = __float2bfloat16(__expf(lv + mr - M));
      __hip_bfloat16 hr = __float2bfloat16(__expf(rv - mr));
      ve = *reinterpret_cast<short*>(&he);
      vr = *reinterpret_cast<short*>(&hr);
    }
    elT[i*S1STR + k] = ve;
    erT[i*S1STR + k] = vr;
  }
  __syncthreads();

  size_t obase = ((size_t)(b*NSMAX + s)) * KK;
  // zero the r>=90 pads (stage2's K coverage needs them exactly 0)
  for (int idx = tid; idx < S * (KP - S); idx += 256){
    int l = idx / (KP - S), rr2 = S + (idx - l * (KP - S));
    Og[obase + (size_t)l*KP + rr2] = __float2bfloat16(0.f);
  }

  int wid = tid >> 6, lane = tid & 63;
  int rr = lane & 15, hi = lane >> 4;
  int ksteps = Kpad >> 5;
  for (int j = 0; j < 9; ++j){           // 36 tiles over 4 waves
    int t = wid * 9 + j;
    int tr = t / 6, tc = t - tr * 6;
    int ar = tr*16 + rr, br = tc*16 + rr;
    f32x4 acc = {0.f, 0.f, 0.f, 0.f};
    for (int ks = 0; ks < ksteps; ++ks){
      int kb = ks*32 + hi*8;
      bf16x8 af = *(bf16x8*)&elT[ar*S1STR + kb];
      bf16x8 bf2 = *(bf16x8*)&erT[br*S1STR + kb];
      acc = __builtin_amdgcn_mfma_f32_16x16x32_bf16(af, bf2, acc, 0, 0, 0);
    }
    int rcol = tc*16 + rr;
    if (rcol < S){
      #pragma unroll
      for (int q = 0; q < 4; ++q){
        int l = tr*16 + hi*4 + q;
        if (l < S) Og[obase + (size_t)l*KP + rcol] = __float2bfloat16(acc[q]);
      }
    }
  }
}

// MFMA split-K GEMM (8 waves = 2 Mtiles x 4 Ntiles), single-barrier register
// double-buffer, with finalize fused via split-K arrival counter.
__global__ __launch_bounds__(512) void stage2f(int w, int ns, int ntiles,
                                               const __hip_bfloat16* __restrict__ erule,
                                               const __hip_bfloat16* __restrict__ Og,
                                               float* __restrict__ Cpart,
                                               const float* __restrict__ Mbuf,
                                               const float* __restrict__ m_rule,
                                               float* __restrict__ beta,
                                               float* __restrict__ mb,
                                               int* __restrict__ counters){
  int kc = blockIdx.x, b = blockIdx.y, tid = threadIdx.x;
  __shared__ __align__(16) short lds[2 * MTOT];   // 27.6 KB (dbuf)
  __shared__ int sOld;
  int wid = tid >> 6, lane = tid & 63;
  int mt = wid & 1, nt = wid >> 1;
  f32x4 acc = {0.f, 0.f, 0.f, 0.f};

  // zero both buffers once: never-staged rows contribute exact 0
  for (int i = tid; i < 2*MTOT; i += 512) lds[i] = 0;

  int slot = tid & 7;
  int aRow = (tid >> 3) & 31;                 // threads 0..255 -> A rows 0..31
  bool aDo = (tid < 256) && (aRow < NT);
  int bRow = tid >> 3;                        // 512 threads -> B rows 0..63
  bool bDo = bRow < ns;
  const __hip_bfloat16* aSrc = erule + ((size_t)(b*NT + (aDo ? aRow : 0))) * KK + slot * 8;
  const __hip_bfloat16* bSrc = Og    + ((size_t)(b*NSMAX + (bDo ? bRow : 0))) * KK + slot * 8;
  int aOff = aRow * MLSTR + slot * 8;
  int bOff = AOFFE + bRow * MLSTR + slot * 8;

  int arow = mt*16 + (lane & 15);
  int brow = nt*16 + (lane & 15);
  int hi = lane >> 4;
  bool active = nt < ntiles;
  int t0 = kc * TPC;

  uint4 ra, rb;
  if (aDo) ra = *(const uint4*)(aSrc + (size_t)t0 * KT2);
  if (bDo) rb = *(const uint4*)(bSrc + (size_t)t0 * KT2);
  __syncthreads();   // zero-fill complete before first data writes

  int cur = 0;
  for (int tt = 0; tt < TPC; ++tt){
    if (aDo) *(uint4*)&lds[cur*MTOT + aOff] = ra;
    if (bDo) *(uint4*)&lds[cur*MTOT + bOff] = rb;
    if (tt + 1 < TPC){
      size_t koff = (size_t)(t0 + tt + 1) * KT2;
      if (aDo) ra = *(const uint4*)(aSrc + koff);
      if (bDo) rb = *(const uint4*)(bSrc + koff);
    }
    __syncthreads();   // buf[cur] staged; also proves compute(tt-1) done on buf[cur^1]
    if (active){
      #pragma unroll
      for (int ks = 0; ks < 2; ++ks){
        int sb = ks*4 + hi;
        bf16x8 af = *(bf16x8*)&lds[cur*MTOT + arow*MLSTR + sb*8];
        bf16x8 bf2 = *(bf16x8*)&lds[cur*MTOT + AOFFE + brow*MLSTR + sb*8];
        acc = __builtin_amdgcn_mfma_f32_16x16x32_bf16(af, bf2, acc, 0, 0, 0);
      }
    }
    cur ^= 1;
  }

  if (active){
    float* cp = Cpart + ((size_t)(kc*B + b)) * CELLS;
    int scol = nt*16 + (lane & 15);
    if (scol < ns){
      #pragma unroll
      for (int r = 0; r < 4; ++r){
        int p = mt*16 + hi*4 + r;
        if (p < NT) cp[p*ns + scol] = acc[r];
      }
    }
  }

  // ---- fused finalize: last-arriving of the KSPL blocks for this b ----
  __threadfence();                      // release our Cpart writes (device scope)
  __syncthreads();
  if (tid == 0) sOld = atomicAdd(&counters[b], 1);
  __syncthreads();
  if (sOld == KSPL - 1){
    __threadfence();                    // acquire: see all blocks' Cpart writes
    float* vals = (float*)lds;          // reuse LDS (5.9 KB needed)
    for (int cell = tid; cell < NT * ns; cell += 512){
      int p = cell / ns, si = cell - p * ns;
      float sum = 0.f;
      #pragma unroll
      for (int q = 0; q < KSPL; ++q) sum += Cpart[((size_t)(q*B + b))*CELLS + cell];
      float v = __logf(fmaxf(sum, 1e-37f)) + Mbuf[b*NSMAX + si] + m_rule[b*NT + p];
      beta[((b*NP1 + si)*NP1 + (si + w))*S + p] = v;
      vals[si*NT + p] = v;
    }
    __syncthreads();
    if (tid < ns){
      float m = NEGF;
      for (int p = 0; p < NT; ++p) m = fmaxf(m, vals[tid*NT + p]);
      mb[(b*NP1 + tid)*NP1 + (tid + w)] = m;
    }
    if (tid == 0) counters[b] = 0;      // ready for next width / next replay
  }
}

__global__ void root_lse(const float* __restrict__ beta, const float* __restrict__ root,
                         float* __restrict__ out){
  int b = blockIdx.x, j = threadIdx.x;
  float v = (j < NT) ? beta[((b*NP1 + 0)*NP1 + N)*S + j] + root[b*NT + j] : NEGF;
  float m = v;
  #pragma unroll
  for (int off = 32; off > 0; off >>= 1) m = fmaxf(m, __shfl_xor(m, off));
  float ex = __expf(v - m);
  #pragma unroll
  for (int off = 32; off > 0; off >>= 1) ex += __shfl_xor(ex, off);
  if (j == 0) out[b] = __logf(ex) + m;
}

} // namespace

extern "C" void kernel_launch(void* const* d_in, const int* in_sizes, int n_in,
                              void* d_out, int out_size, void* d_ws, size_t ws_size,
                              hipStream_t stream){
  (void)in_sizes; (void)n_in; (void)out_size; (void)ws_size;
  const float* unary = (const float*)d_in[0];
  const float* rule  = (const float*)d_in[1];
  const float* root  = (const float*)d_in[2];

  char* ws = (char*)d_ws;
  size_t off = 0;
  auto alloc = [&](size_t bytes) -> void* {
    void* p = ws + off;
    off += (bytes + 255) & ~(size_t)255;
    return p;
  };
  float* beta   = (float*)alloc(sizeof(float) * (size_t)B * NP1 * NP1 * S);
  float* mb     = (float*)alloc(sizeof(float) * (size_t)B * NP1 * NP1);
  float* m_rule = (float*)alloc(sizeof(float) * B * NT);
  float* Mbuf   = (float*)alloc(sizeof(float) * B * NSMAX);
  float* Cpart  = (float*)alloc(sizeof(float) * KSPL * B * CELLS);
  int*   cnts   = (int*)alloc(sizeof(int) * B);
  __hip_bfloat16* erule = (__hip_bfloat16*)alloc(sizeof(__hip_bfloat16) * (size_t)B * NT * KK);
  __hip_bfloat16* Og    = (__hip_bfloat16*)alloc(sizeof(__hip_bfloat16) * (size_t)B * NSMAX * KK);

  zero_counters<<<dim3(1), dim3(64), 0, stream>>>(cnts);
  int betaCount = B * NP1 * NP1 * S;
  fill_neg<<<dim3((betaCount + 255) / 256), dim3(256), 0, stream>>>(beta, betaCount);
  int mbCount = B * NP1 * NP1;
  fill_neg<<<dim3((mbCount + 255) / 256), dim3(256), 0, stream>>>(mb, mbCount);
  unary_init<<<dim3(N, B), dim3(64), 0, stream>>>(unary, beta, mb);
  rule_prep<<<dim3(NT, B), dim3(256), 0, stream>>>(rule, m_rule, erule);

  for (int w = 2; w <= N; ++w){
    int ns = N - w + 1;
    int ntiles = (ns + 15) >> 4;
    stage1<<<dim3(ns, B), dim3(256), 0, stream>>>(w, beta, mb, Mbuf, Og);
    stage2f<<<dim3(KSPL, B), dim3(512), 0, stream>>>(w, ns, ntiles, erule, Og, Cpart,
                                                     Mbuf, m_rule, beta, mb, cnts);
  }
  root_lse<<<dim3(B), dim3(64), 0, stream>>>(beta, root, (float*)d_out);
}

// Round 9
// 1821.602 us; speedup vs baseline: 4.7538x; 4.7538x over previous
//
#include <hip/hip_runtime.h>
#include <hip/hip_bf16.h>

#define NEGF (-1000000000.0f)

namespace {

constexpr int B  = 64;
constexpr int N  = 50;
constexpr int NT = 30;
constexpr int T  = 60;
constexpr int S  = 90;          // NT + T
constexpr int NP1 = N + 1;      // 51
constexpr int NSMAX = N - 1;    // 49
constexpr int SS = S * S;       // 8100
constexpr int CELLS = NT * NSMAX; // 1470

// ---- padded K layout ----
constexpr int KP  = 96;          // padded r-dim per l (zero pads at r>=90)
constexpr int KK  = S * KP;      // 8640
constexpr int KSPL = 9;          // split-K chunks
constexpr int KT2 = 64;          // K-tile per LDS staging step
constexpr int NKT = KK / KT2;    // 135
constexpr int TPC = NKT / KSPL;  // 15 tiles per chunk
constexpr int MLSTR = 72;        // LDS row stride (shorts); 144B: b128-aligned, 2-way banks
constexpr int MAROWS = 32;
constexpr int MBROWS = 64;
constexpr int AOFFE = MAROWS * MLSTR;
constexpr int MTOT  = (MAROWS + MBROWS) * MLSTR;   // 6912 shorts = 13.8 KB

// ---- stage1 MFMA layout ----
constexpr int S1R = 96;          // padded state rows: 6 tiles of 16
constexpr int S1STR = 72;        // row stride in shorts (144B, b128-aligned)

using bf16x8 = __attribute__((ext_vector_type(8))) short;
using f32x4  = __attribute__((ext_vector_type(4))) float;

__global__ void fill_neg(float* __restrict__ p, int count){
  int i = blockIdx.x * blockDim.x + threadIdx.x;
  if (i < count) p[i] = NEGF;
}

// width-1 spans: terminal states get unary scores; also per-span state-max mb.
__global__ void unary_init(const float* __restrict__ unary, float* __restrict__ beta,
                           float* __restrict__ mb){
  int k = blockIdx.x, b = blockIdx.y, j = threadIdx.x;
  float v = NEGF;
  if (j < T){
    v = unary[(b*N + k)*T + j];
    beta[((b*NP1 + k)*NP1 + (k+1))*S + NT + j] = v;
  }
  #pragma unroll
  for (int off = 32; off > 0; off >>= 1) v = fmaxf(v, __shfl_down(v, off));
  if (j == 0) mb[(b*NP1 + k)*NP1 + (k+1)] = v;
}

// Single-pass (LDS-cached) rule prep.
__global__ __launch_bounds__(256) void rule_prep(const float* __restrict__ rule,
                                                 float* __restrict__ m_rule,
                                                 __hip_bfloat16* __restrict__ erule){
  int p = blockIdx.x, b = blockIdx.y, tid = threadIdx.x;
  int base = (b*NT + p) * SS;
  size_t obase = ((size_t)(b*NT + p)) * KK;
  __shared__ float srule[SS];   // 32.4 KB
  float lm = NEGF;
  for (int i = tid; i < SS; i += 256){
    float v = rule[base + i];
    srule[i] = v;
    lm = fmaxf(lm, v);
  }
  #pragma unroll
  for (int off = 32; off > 0; off >>= 1) lm = fmaxf(lm, __shfl_xor(lm, off));
  __shared__ float wmax[4];
  __shared__ float sm;
  if ((tid & 63) == 0) wmax[tid >> 6] = lm;
  __syncthreads();
  if (tid == 0){
    float m = fmaxf(fmaxf(wmax[0], wmax[1]), fmaxf(wmax[2], wmax[3]));
    m_rule[b*NT + p] = m;
    sm = m;
  }
  __syncthreads();
  float m = sm;
  for (int i = tid; i < KK; i += 256){
    int l = i / KP, rr = i - l * KP;
    float v = (rr < S) ? __expf(srule[l*S + rr] - m) : 0.f;
    erule[obase + i] = __float2bfloat16(v);
  }
}

// Per span (b,s) of width w: O[l,r] = sum_k el[k,l]*er[k,r] via MFMA (proven R8).
__global__ __launch_bounds__(256) void stage1(int w, const float* __restrict__ beta,
                                              const float* __restrict__ mb,
                                              float* __restrict__ Mbuf,
                                              __hip_bfloat16* __restrict__ Og){
  int s = blockIdx.x, b = blockIdx.y, e = s + w, tid = threadIdx.x;
  int K = w - 1;
  int Kpad = (K + 31) & ~31;          // 32 or 64
  __shared__ float smr[NSMAX];
  __shared__ float stmp[NSMAX];
  __shared__ float sM;
  __shared__ __align__(16) short elT[S1R * S1STR];  // 13.8 KB
  __shared__ __align__(16) short erT[S1R * S1STR];  // 13.8 KB

  if (tid < K){
    int u = s + tid + 1;
    float ml = mb[(b*NP1 + s)*NP1 + u];
    float mr = mb[(b*NP1 + u)*NP1 + e];
    smr[tid] = mr;
    stmp[tid] = ml + mr;
  }
  __syncthreads();
  if (tid == 0){
    float M = NEGF;
    for (int k = 0; k < K; ++k) M = fmaxf(M, stmp[k]);
    sM = M;
    Mbuf[b*NSMAX + s] = M;
  }
  __syncthreads();
  float M = sM;

  int items = S1R * Kpad;
  for (int idx = tid; idx < items; idx += 256){
    int k = idx / S1R, i = idx - k * S1R;   // i fastest -> coalesced beta reads
    short ve = 0, vr = 0;
    if (i < S && k < K){
      int u = s + k + 1;
      float mr = smr[k];
      float lv = beta[((b*NP1 + s)*NP1 + u)*S + i];
      float rv = beta[((b*NP1 + u)*NP1 + e)*S + i];
      __hip_bfloat16 he = __float2bfloat16(__expf(lv + mr - M));
      __hip_bfloat16 hr = __float2bfloat16(__expf(rv - mr));
      ve = *reinterpret_cast<short*>(&he);
      vr = *reinterpret_cast<short*>(&hr);
    }
    elT[i*S1STR + k] = ve;
    erT[i*S1STR + k] = vr;
  }
  __syncthreads();

  size_t obase = ((size_t)(b*NSMAX + s)) * KK;
  for (int idx = tid; idx < S * (KP - S); idx += 256){
    int l = idx / (KP - S), rr2 = S + (idx - l * (KP - S));
    Og[obase + (size_t)l*KP + rr2] = __float2bfloat16(0.f);
  }

  int wid = tid >> 6, lane = tid & 63;
  int rr = lane & 15, hi = lane >> 4;
  int ksteps = Kpad >> 5;
  for (int j = 0; j < 9; ++j){           // 36 tiles over 4 waves
    int t = wid * 9 + j;
    int tr = t / 6, tc = t - tr * 6;
    int ar = tr*16 + rr, br = tc*16 + rr;
    f32x4 acc = {0.f, 0.f, 0.f, 0.f};
    for (int ks = 0; ks < ksteps; ++ks){
      int kb = ks*32 + hi*8;
      bf16x8 af = *(bf16x8*)&elT[ar*S1STR + kb];
      bf16x8 bf2 = *(bf16x8*)&erT[br*S1STR + kb];
      acc = __builtin_amdgcn_mfma_f32_16x16x32_bf16(af, bf2, acc, 0, 0, 0);
    }
    int rcol = tc*16 + rr;
    if (rcol < S){
      #pragma unroll
      for (int q = 0; q < 4; ++q){
        int l = tr*16 + hi*4 + q;
        if (l < S) Og[obase + (size_t)l*KP + rcol] = __float2bfloat16(acc[q]);
      }
    }
  }
}

// MFMA split-K GEMM (8 waves = 2 Mtiles x 4 Ntiles), single-barrier register
// double-buffer. NO device-scope fences (R8 lesson: __threadfence's cross-XCD
// L2 flush per block cost 10x); finalize is a separate kernel again.
__global__ __launch_bounds__(512) void stage2(int ns, int ntiles,
                                              const __hip_bfloat16* __restrict__ erule,
                                              const __hip_bfloat16* __restrict__ Og,
                                              float* __restrict__ Cpart){
  int kc = blockIdx.x, b = blockIdx.y, tid = threadIdx.x;
  __shared__ __align__(16) short lds[2 * MTOT];   // 27.6 KB (dbuf)
  int wid = tid >> 6, lane = tid & 63;
  int mt = wid & 1, nt = wid >> 1;
  f32x4 acc = {0.f, 0.f, 0.f, 0.f};

  for (int i = tid; i < 2*MTOT; i += 512) lds[i] = 0;

  int slot = tid & 7;
  int aRow = (tid >> 3) & 31;                 // threads 0..255 -> A rows 0..31
  bool aDo = (tid < 256) && (aRow < NT);
  int bRow = tid >> 3;                        // 512 threads -> B rows 0..63
  bool bDo = bRow < ns;
  const __hip_bfloat16* aSrc = erule + ((size_t)(b*NT + (aDo ? aRow : 0))) * KK + slot * 8;
  const __hip_bfloat16* bSrc = Og    + ((size_t)(b*NSMAX + (bDo ? bRow : 0))) * KK + slot * 8;
  int aOff = aRow * MLSTR + slot * 8;
  int bOff = AOFFE + bRow * MLSTR + slot * 8;

  int arow = mt*16 + (lane & 15);
  int brow = nt*16 + (lane & 15);
  int hi = lane >> 4;
  bool active = nt < ntiles;
  int t0 = kc * TPC;

  uint4 ra, rb;
  if (aDo) ra = *(const uint4*)(aSrc + (size_t)t0 * KT2);
  if (bDo) rb = *(const uint4*)(bSrc + (size_t)t0 * KT2);
  __syncthreads();   // zero-fill complete before first data writes

  int cur = 0;
  for (int tt = 0; tt < TPC; ++tt){
    if (aDo) *(uint4*)&lds[cur*MTOT + aOff] = ra;
    if (bDo) *(uint4*)&lds[cur*MTOT + bOff] = rb;
    if (tt + 1 < TPC){
      size_t koff = (size_t)(t0 + tt + 1) * KT2;
      if (aDo) ra = *(const uint4*)(aSrc + koff);
      if (bDo) rb = *(const uint4*)(bSrc + koff);
    }
    __syncthreads();   // buf[cur] staged; compute(tt-1) on buf[cur^1] done
    if (active){
      #pragma unroll
      for (int ks = 0; ks < 2; ++ks){
        int sb = ks*4 + hi;
        bf16x8 af = *(bf16x8*)&lds[cur*MTOT + arow*MLSTR + sb*8];
        bf16x8 bf2 = *(bf16x8*)&lds[cur*MTOT + AOFFE + brow*MLSTR + sb*8];
        acc = __builtin_amdgcn_mfma_f32_16x16x32_bf16(af, bf2, acc, 0, 0, 0);
      }
    }
    cur ^= 1;
  }

  if (active){
    float* cp = Cpart + ((size_t)(kc*B + b)) * CELLS;
    int scol = nt*16 + (lane & 15);
    if (scol < ns){
      #pragma unroll
      for (int r = 0; r < 4; ++r){
        int p = mt*16 + hi*4 + r;
        if (p < NT) cp[p*ns + scol] = acc[r];
      }
    }
  }
}

// beta[b,s,s+w,p] = log(sum_kc Cpart) + M[b,s] + m_rule[b,p]; mb = max_p.
__global__ __launch_bounds__(256) void finalize(int w, int ns, const float* __restrict__ Cpart,
                                                const float* __restrict__ Mbuf,
                                                const float* __restrict__ m_rule,
                                                float* __restrict__ beta, float* __restrict__ mb){
  int b = blockIdx.x, tid = threadIdx.x;
  __shared__ float vals[CELLS];
  for (int cell = tid; cell < NT * ns; cell += 256){
    int p = cell / ns, si = cell - p * ns;
    float sum = 0.f;
    #pragma unroll
    for (int kc = 0; kc < KSPL; ++kc) sum += Cpart[((size_t)(kc*B + b))*CELLS + cell];
    float v = __logf(fmaxf(sum, 1e-37f)) + Mbuf[b*NSMAX + si] + m_rule[b*NT + p];
    beta[((b*NP1 + si)*NP1 + (si + w))*S + p] = v;
    vals[si*NT + p] = v;
  }
  __syncthreads();
  if (tid < ns){
    float m = NEGF;
    for (int p = 0; p < NT; ++p) m = fmaxf(m, vals[tid*NT + p]);
    mb[(b*NP1 + tid)*NP1 + (tid + w)] = m;
  }
}

__global__ void root_lse(const float* __restrict__ beta, const float* __restrict__ root,
                         float* __restrict__ out){
  int b = blockIdx.x, j = threadIdx.x;
  float v = (j < NT) ? beta[((b*NP1 + 0)*NP1 + N)*S + j] + root[b*NT + j] : NEGF;
  float m = v;
  #pragma unroll
  for (int off = 32; off > 0; off >>= 1) m = fmaxf(m, __shfl_xor(m, off));
  float ex = __expf(v - m);
  #pragma unroll
  for (int off = 32; off > 0; off >>= 1) ex += __shfl_xor(ex, off);
  if (j == 0) out[b] = __logf(ex) + m;
}

} // namespace

extern "C" void kernel_launch(void* const* d_in, const int* in_sizes, int n_in,
                              void* d_out, int out_size, void* d_ws, size_t ws_size,
                              hipStream_t stream){
  (void)in_sizes; (void)n_in; (void)out_size; (void)ws_size;
  const float* unary = (const float*)d_in[0];
  const float* rule  = (const float*)d_in[1];
  const float* root  = (const float*)d_in[2];

  char* ws = (char*)d_ws;
  size_t off = 0;
  auto alloc = [&](size_t bytes) -> void* {
    void* p = ws + off;
    off += (bytes + 255) & ~(size_t)255;
    return p;
  };
  float* beta   = (float*)alloc(sizeof(float) * (size_t)B * NP1 * NP1 * S);
  float* mb     = (float*)alloc(sizeof(float) * (size_t)B * NP1 * NP1);
  float* m_rule = (float*)alloc(sizeof(float) * B * NT);
  float* Mbuf   = (float*)alloc(sizeof(float) * B * NSMAX);
  float* Cpart  = (float*)alloc(sizeof(float) * KSPL * B * CELLS);
  __hip_bfloat16* erule = (__hip_bfloat16*)alloc(sizeof(__hip_bfloat16) * (size_t)B * NT * KK);
  __hip_bfloat16* Og    = (__hip_bfloat16*)alloc(sizeof(__hip_bfloat16) * (size_t)B * NSMAX * KK);

  int betaCount = B * NP1 * NP1 * S;
  fill_neg<<<dim3((betaCount + 255) / 256), dim3(256), 0, stream>>>(beta, betaCount);
  int mbCount = B * NP1 * NP1;
  fill_neg<<<dim3((mbCount + 255) / 256), dim3(256), 0, stream>>>(mb, mbCount);
  unary_init<<<dim3(N, B), dim3(64), 0, stream>>>(unary, beta, mb);
  rule_prep<<<dim3(NT, B), dim3(256), 0, stream>>>(rule, m_rule, erule);

  for (int w = 2; w <= N; ++w){
    int ns = N - w + 1;
    int ntiles = (ns + 15) >> 4;
    stage1<<<dim3(ns, B), dim3(256), 0, stream>>>(w, beta, mb, Mbuf, Og);
    stage2<<<dim3(KSPL, B), dim3(512), 0, stream>>>(ns, ntiles, erule, Og, Cpart);
    finalize<<<dim3(B), dim3(256), 0, stream>>>(w, ns, Cpart, Mbuf, m_rule, beta, mb);
  }
  root_lse<<<dim3(B), dim3(64), 0, stream>>>(beta, root, (float*)d_out);
}

// Round 10
// 1700.268 us; speedup vs baseline: 5.0931x; 1.0714x over previous
//
#include <hip/hip_runtime.h>
#include <hip/hip_bf16.h>

#define NEGF (-1000000000.0f)

namespace {

constexpr int B  = 64;
constexpr int N  = 50;
constexpr int NT = 30;
constexpr int T  = 60;
constexpr int S  = 90;          // NT + T
constexpr int NP1 = N + 1;      // 51
constexpr int NSMAX = N - 1;    // 49
constexpr int SS = S * S;       // 8100
constexpr int CELLS = NT * NSMAX; // 1470

// ---- padded K layout ----
constexpr int KP  = 96;          // padded r-dim per l (erule pads are exact 0)
constexpr int KK  = S * KP;      // 8640
constexpr int KSPL = 15;         // split-K chunks (was 9; more blocks -> latency hiding)
constexpr int KT2 = 64;          // K-tile per LDS staging step
constexpr int NKT = KK / KT2;    // 135
constexpr int TPC = NKT / KSPL;  // 9 tiles per chunk
constexpr int MLSTR = 72;        // LDS row stride (shorts); 144B: b128-aligned, 2-way banks
constexpr int MAROWS = 32;
constexpr int MBROWS = 64;
constexpr int AOFFE = MAROWS * MLSTR;
constexpr int MTOT  = (MAROWS + MBROWS) * MLSTR;   // 6912 shorts = 13.8 KB

// ---- stage1 MFMA layout ----
constexpr int S1R = 96;          // padded state rows: 6 tiles of 16
constexpr int S1STR = 72;        // row stride in shorts (144B, b128-aligned)

using bf16x8 = __attribute__((ext_vector_type(8))) short;
using f32x4  = __attribute__((ext_vector_type(4))) float;

// width-1 spans: terminal states get unary scores; also per-span state-max mb.
// (beta is NOT pre-filled with NEG anymore: stage1 masks invalid states by
//  child width, so unwritten beta cells are never consumed.)
__global__ void unary_init(const float* __restrict__ unary, float* __restrict__ beta,
                           float* __restrict__ mb){
  int k = blockIdx.x, b = blockIdx.y, j = threadIdx.x;
  float v = NEGF;
  if (j < T){
    v = unary[(b*N + k)*T + j];
    beta[((b*NP1 + k)*NP1 + (k+1))*S + NT + j] = v;
  }
  #pragma unroll
  for (int off = 32; off > 0; off >>= 1) v = fmaxf(v, __shfl_down(v, off));
  if (j == 0) mb[(b*NP1 + k)*NP1 + (k+1)] = v;
}

// Vectorized 2-pass rule prep: pass1 float4 max; pass2 float2 -> 2 exps ->
// packed 2xbf16 uint store. No big LDS (R9 lesson: 32KB srule capped occupancy).
__global__ __launch_bounds__(256) void rule_prep(const float* __restrict__ rule,
                                                 float* __restrict__ m_rule,
                                                 __hip_bfloat16* __restrict__ erule){
  int p = blockIdx.x, b = blockIdx.y, tid = threadIdx.x;
  size_t base = (size_t)(b*NT + p) * SS;
  size_t obase = (size_t)(b*NT + p) * KK;
  const float4* r4 = (const float4*)(rule + base);
  float lm = NEGF;
  for (int i = tid; i < SS/4; i += 256){
    float4 v = r4[i];
    lm = fmaxf(fmaxf(lm, fmaxf(v.x, v.y)), fmaxf(v.z, v.w));
  }
  #pragma unroll
  for (int off = 32; off > 0; off >>= 1) lm = fmaxf(lm, __shfl_xor(lm, off));
  __shared__ float wmax[4];
  __shared__ float sm;
  if ((tid & 63) == 0) wmax[tid >> 6] = lm;
  __syncthreads();
  if (tid == 0){
    float m = fmaxf(fmaxf(wmax[0], wmax[1]), fmaxf(wmax[2], wmax[3]));
    m_rule[b*NT + p] = m;
    sm = m;
  }
  __syncthreads();
  float m = sm;
  // 48 r-pairs per l (pairs 45..47 are the zero pads r>=90)
  for (int idx = tid; idx < S * 48; idx += 256){
    int l = idx / 48, pr = idx - l * 48;
    int r = pr * 2;
    unsigned int out = 0;
    if (r < S){
      float2 v = *(const float2*)(rule + base + l*S + r);
      __hip_bfloat16 h0 = __float2bfloat16(__expf(v.x - m));
      __hip_bfloat16 h1 = __float2bfloat16(__expf(v.y - m));
      out = (unsigned int)*(unsigned short*)&h0 |
            ((unsigned int)*(unsigned short*)&h1 << 16);
    }
    *(unsigned int*)&erule[obase + l*KP + r] = out;
  }
}

// Per span (b,s) of width w: O[l,r] = sum_k el[k,l]*er[k,r] via MFMA.
// Validity masking by child width replaces the global NEG fill.
__global__ __launch_bounds__(256) void stage1(int w, const float* __restrict__ beta,
                                              const float* __restrict__ mb,
                                              float* __restrict__ Mbuf,
                                              __hip_bfloat16* __restrict__ Og){
  int s = blockIdx.x, b = blockIdx.y, e = s + w, tid = threadIdx.x;
  int K = w - 1;
  int Kpad = (K + 31) & ~31;          // 32 or 64
  __shared__ float smr[NSMAX];
  __shared__ float stmp[NSMAX];
  __shared__ float sM;
  __shared__ __align__(16) short elT[S1R * S1STR];  // 13.8 KB
  __shared__ __align__(16) short erT[S1R * S1STR];  // 13.8 KB

  if (tid < K){
    int u = s + tid + 1;
    float ml = mb[(b*NP1 + s)*NP1 + u];
    float mr = mb[(b*NP1 + u)*NP1 + e];
    smr[tid] = mr;
    stmp[tid] = ml + mr;
  }
  __syncthreads();
  if (tid == 0){
    float M = NEGF;
    for (int k = 0; k < K; ++k) M = fmaxf(M, stmp[k]);
    sM = M;
    Mbuf[b*NSMAX + s] = M;
  }
  __syncthreads();
  float M = sM;

  int items = S1R * Kpad;
  for (int idx = tid; idx < items; idx += 256){
    int k = idx / S1R, i = idx - k * S1R;   // i fastest -> coalesced beta reads
    short ve = 0, vr = 0;
    if (i < S && k < K){
      int u = s + k + 1;
      float mr = smr[k];
      float lv = beta[((b*NP1 + s)*NP1 + u)*S + i];
      float rv = beta[((b*NP1 + u)*NP1 + e)*S + i];
      // left child width = k+1; right child width = K-k. Width-1 cells hold
      // only terminal states (i>=NT); wider cells only nonterminals (i<NT).
      bool lOK = (k == 0)     ? (i >= NT) : (i < NT);
      bool rOK = (k == K - 1) ? (i >= NT) : (i < NT);
      float ev = lOK ? __expf(lv + mr - M) : 0.f;
      float rv2 = rOK ? __expf(rv - mr) : 0.f;
      __hip_bfloat16 he = __float2bfloat16(ev);
      __hip_bfloat16 hr = __float2bfloat16(rv2);
      ve = *reinterpret_cast<short*>(&he);
      vr = *reinterpret_cast<short*>(&hr);
    }
    elT[i*S1STR + k] = ve;
    erT[i*S1STR + k] = vr;
  }
  __syncthreads();

  size_t obase = ((size_t)(b*NSMAX + s)) * KK;
  // NOTE: Og pad columns (r>=90) are left unwritten on purpose — stage2
  // multiplies them against erule pads, which are exact 0.

  int wid = tid >> 6, lane = tid & 63;
  int rr = lane & 15, hi = lane >> 4;
  int ksteps = Kpad >> 5;
  for (int j = 0; j < 9; ++j){           // 36 tiles over 4 waves
    int t = wid * 9 + j;
    int tr = t / 6, tc = t - tr * 6;
    int ar = tr*16 + rr, br = tc*16 + rr;
    f32x4 acc = {0.f, 0.f, 0.f, 0.f};
    for (int ks = 0; ks < ksteps; ++ks){
      int kb = ks*32 + hi*8;
      bf16x8 af = *(bf16x8*)&elT[ar*S1STR + kb];
      bf16x8 bf2 = *(bf16x8*)&erT[br*S1STR + kb];
      acc = __builtin_amdgcn_mfma_f32_16x16x32_bf16(af, bf2, acc, 0, 0, 0);
    }
    int rcol = tc*16 + rr;
    if (rcol < S){
      #pragma unroll
      for (int q = 0; q < 4; ++q){
        int l = tr*16 + hi*4 + q;
        if (l < S) Og[obase + (size_t)l*KP + rcol] = __float2bfloat16(acc[q]);
      }
    }
  }
}

// MFMA split-K GEMM (8 waves = 2 Mtiles x 4 Ntiles), single-barrier register
// double-buffer. No device-scope fences (R8 lesson).
__global__ __launch_bounds__(512) void stage2(int ns, int ntiles,
                                              const __hip_bfloat16* __restrict__ erule,
                                              const __hip_bfloat16* __restrict__ Og,
                                              float* __restrict__ Cpart){
  int kc = blockIdx.x, b = blockIdx.y, tid = threadIdx.x;
  __shared__ __align__(16) short lds[2 * MTOT];   // 27.6 KB (dbuf)
  int wid = tid >> 6, lane = tid & 63;
  int mt = wid & 1, nt = wid >> 1;
  f32x4 acc = {0.f, 0.f, 0.f, 0.f};

  for (int i = tid; i < 2*MTOT; i += 512) lds[i] = 0;

  int slot = tid & 7;
  int aRow = (tid >> 3) & 31;                 // threads 0..255 -> A rows 0..31
  bool aDo = (tid < 256) && (aRow < NT);
  int bRow = tid >> 3;                        // 512 threads -> B rows 0..63
  bool bDo = bRow < ns;
  const __hip_bfloat16* aSrc = erule + ((size_t)(b*NT + (aDo ? aRow : 0))) * KK + slot * 8;
  const __hip_bfloat16* bSrc = Og    + ((size_t)(b*NSMAX + (bDo ? bRow : 0))) * KK + slot * 8;
  int aOff = aRow * MLSTR + slot * 8;
  int bOff = AOFFE + bRow * MLSTR + slot * 8;

  int arow = mt*16 + (lane & 15);
  int brow = nt*16 + (lane & 15);
  int hi = lane >> 4;
  bool active = nt < ntiles;
  int t0 = kc * TPC;

  uint4 ra, rb;
  if (aDo) ra = *(const uint4*)(aSrc + (size_t)t0 * KT2);
  if (bDo) rb = *(const uint4*)(bSrc + (size_t)t0 * KT2);
  __syncthreads();   // zero-fill complete before first data writes

  int cur = 0;
  for (int tt = 0; tt < TPC; ++tt){
    if (aDo) *(uint4*)&lds[cur*MTOT + aOff] = ra;
    if (bDo) *(uint4*)&lds[cur*MTOT + bOff] = rb;
    if (tt + 1 < TPC){
      size_t koff = (size_t)(t0 + tt + 1) * KT2;
      if (aDo) ra = *(const uint4*)(aSrc + koff);
      if (bDo) rb = *(const uint4*)(bSrc + koff);
    }
    __syncthreads();   // buf[cur] staged; compute(tt-1) on buf[cur^1] done
    if (active){
      #pragma unroll
      for (int ks = 0; ks < 2; ++ks){
        int sb = ks*4 + hi;
        bf16x8 af = *(bf16x8*)&lds[cur*MTOT + arow*MLSTR + sb*8];
        bf16x8 bf2 = *(bf16x8*)&lds[cur*MTOT + AOFFE + brow*MLSTR + sb*8];
        acc = __builtin_amdgcn_mfma_f32_16x16x32_bf16(af, bf2, acc, 0, 0, 0);
      }
    }
    cur ^= 1;
  }

  if (active){
    float* cp = Cpart + ((size_t)(kc*B + b)) * CELLS;
    int scol = nt*16 + (lane & 15);
    if (scol < ns){
      #pragma unroll
      for (int r = 0; r < 4; ++r){
        int p = mt*16 + hi*4 + r;
        if (p < NT) cp[p*ns + scol] = acc[r];
      }
    }
  }
}

// beta[b,s,s+w,p] = log(sum_kc Cpart) + M[b,s] + m_rule[b,p]; mb = max_p.
__global__ __launch_bounds__(256) void finalize(int w, int ns, const float* __restrict__ Cpart,
                                                const float* __restrict__ Mbuf,
                                                const float* __restrict__ m_rule,
                                                float* __restrict__ beta, float* __restrict__ mb){
  int b = blockIdx.x, tid = threadIdx.x;
  __shared__ float vals[CELLS];
  for (int cell = tid; cell < NT * ns; cell += 256){
    int p = cell / ns, si = cell - p * ns;
    float sum = 0.f;
    #pragma unroll
    for (int kc = 0; kc < KSPL; ++kc) sum += Cpart[((size_t)(kc*B + b))*CELLS + cell];
    float v = __logf(fmaxf(sum, 1e-37f)) + Mbuf[b*NSMAX + si] + m_rule[b*NT + p];
    beta[((b*NP1 + si)*NP1 + (si + w))*S + p] = v;
    vals[si*NT + p] = v;
  }
  __syncthreads();
  if (tid < ns){
    float m = NEGF;
    for (int p = 0; p < NT; ++p) m = fmaxf(m, vals[tid*NT + p]);
    mb[(b*NP1 + tid)*NP1 + (tid + w)] = m;
  }
}

__global__ void root_lse(const float* __restrict__ beta, const float* __restrict__ root,
                         float* __restrict__ out){
  int b = blockIdx.x, j = threadIdx.x;
  float v = (j < NT) ? beta[((b*NP1 + 0)*NP1 + N)*S + j] + root[b*NT + j] : NEGF;
  float m = v;
  #pragma unroll
  for (int off = 32; off > 0; off >>= 1) m = fmaxf(m, __shfl_xor(m, off));
  float ex = __expf(v - m);
  #pragma unroll
  for (int off = 32; off > 0; off >>= 1) ex += __shfl_xor(ex, off);
  if (j == 0) out[b] = __logf(ex) + m;
}

} // namespace

extern "C" void kernel_launch(void* const* d_in, const int* in_sizes, int n_in,
                              void* d_out, int out_size, void* d_ws, size_t ws_size,
                              hipStream_t stream){
  (void)in_sizes; (void)n_in; (void)out_size; (void)ws_size;
  const float* unary = (const float*)d_in[0];
  const float* rule  = (const float*)d_in[1];
  const float* root  = (const float*)d_in[2];

  char* ws = (char*)d_ws;
  size_t off = 0;
  auto alloc = [&](size_t bytes) -> void* {
    void* p = ws + off;
    off += (bytes + 255) & ~(size_t)255;
    return p;
  };
  float* beta   = (float*)alloc(sizeof(float) * (size_t)B * NP1 * NP1 * S);
  float* mb     = (float*)alloc(sizeof(float) * (size_t)B * NP1 * NP1);
  float* m_rule = (float*)alloc(sizeof(float) * B * NT);
  float* Mbuf   = (float*)alloc(sizeof(float) * B * NSMAX);
  float* Cpart  = (float*)alloc(sizeof(float) * KSPL * B * CELLS);           // 5.6 MB
  __hip_bfloat16* erule = (__hip_bfloat16*)alloc(sizeof(__hip_bfloat16) * (size_t)B * NT * KK);
  __hip_bfloat16* Og    = (__hip_bfloat16*)alloc(sizeof(__hip_bfloat16) * (size_t)B * NSMAX * KK);

  unary_init<<<dim3(N, B), dim3(64), 0, stream>>>(unary, beta, mb);
  rule_prep<<<dim3(NT, B), dim3(256), 0, stream>>>(rule, m_rule, erule);

  for (int w = 2; w <= N; ++w){
    int ns = N - w + 1;
    int ntiles = (ns + 15) >> 4;
    stage1<<<dim3(ns, B), dim3(256), 0, stream>>>(w, beta, mb, Mbuf, Og);
    stage2<<<dim3(KSPL, B), dim3(512), 0, stream>>>(ns, ntiles, erule, Og, Cpart);
    finalize<<<dim3(B), dim3(256), 0, stream>>>(w, ns, Cpart, Mbuf, m_rule, beta, mb);
  }
  root_lse<<<dim3(B), dim3(64), 0, stream>>>(beta, root, (float*)d_out);
}